// Round 2
// baseline (166.059 us; speedup 1.0000x reference)
//
#include <hip/hip_runtime.h>
#include <stdint.h>

#define Bb 2
#define Ss 2048
#define Dd 1024
#define Hh 8
#define Ee 128
#define KWW 16
#define Mm (Bb*Ss)   // 4096
#define Kk 1024      // K for both GEMMs

typedef unsigned short u16;
typedef __attribute__((ext_vector_type(8))) _Float16 f16x8;  // 8 fp16 (4 VGPRs)
typedef __attribute__((ext_vector_type(4))) float f32x4;
typedef __attribute__((ext_vector_type(2))) _Float16 h2;

// fp32 -> fp16 (RTN)
__device__ __forceinline__ u16 f2h(float f) {
  union { _Float16 h; u16 u; } v; v.h = (_Float16)f; return v.u;
}
__device__ __forceinline__ float h2f(u16 u) {
  union { u16 u; _Float16 h; } v; v.u = u; return (float)v.h;
}
__device__ __forceinline__ float h2f_lo(uint32_t w) { return h2f((u16)(w & 0xFFFF)); }
__device__ __forceinline__ float h2f_hi(uint32_t w) { return h2f((u16)(w >> 16)); }
__device__ __forceinline__ h2 as_h2(uint32_t w) {
  union { uint32_t u; h2 h; } v; v.u = w; return v.h;
}
__device__ __forceinline__ h2 mk_h2(float a, float b) {
  h2 r; r[0] = (_Float16)a; r[1] = (_Float16)b; return r;
}

// async global->LDS, 16B per lane. LDS dst must be wave-uniform base; HW scatters lane*16B.
__device__ __forceinline__ void gll16(const void* g, void* l) {
  __builtin_amdgcn_global_load_lds((const __attribute__((address_space(1))) void*)g,
                                   (__attribute__((address_space(3))) void*)l, 16, 0, 0);
}

// ---------------- fused prep kernel ----------------
// Weights are emitted FRAGMENT-MAJOR: [kc][n][8] per panel (kc = k/8), so the
// GEMM B-operand is loaded straight from global as per-lane b128 (no LDS for B).
// blocks [0,4096): cast x f32->f16
// blocks [4096,7168): Wq/Wk/Wv [h][D][E] -> wT[z][kc][n(E)][8], z=proj*8+h
// blocks [7168,8192): Wo [h*E][D] -> woT[nb][kc][nn][8], n = nb*128+nn over D
__global__ __launch_bounds__(256) void prep(
    const float* __restrict__ x, const float* __restrict__ Wq,
    const float* __restrict__ Wk, const float* __restrict__ Wv,
    const float* __restrict__ Wo,
    u16* __restrict__ xh, u16* __restrict__ wT, u16* __restrict__ woT) {
  const int bid = blockIdx.x;
  const int tid = threadIdx.x;
  if (bid < 4096) {
    int i = (bid * 256 + tid) * 4;
    float4 f = *(const float4*)(x + i);
    uint64_t pk = (uint64_t)f2h(f.x) | ((uint64_t)f2h(f.y) << 16) |
                  ((uint64_t)f2h(f.z) << 32) | ((uint64_t)f2h(f.w) << 48);
    *(uint64_t*)(xh + i) = pk;
    return;
  }
  __shared__ float tile[32][33];  // +1 pad: bank-conflict-free
  const int tx = tid & 31, ty = tid >> 5;  // (32,8) shape
  if (bid < 4096 + 3072) {
    const int idx = bid - 4096;
    const int z = idx >> 7, rem = idx & 127;
    const int h = z & 7;
    const float* W = (z < 8) ? Wq : (z < 16) ? Wk : Wv;
    const float* ib = W + (size_t)h * Dd * Ee;
    u16* ob = wT + (size_t)z * Ee * Kk;   // 131072 elems = [kc 128][n 128][8]
    const int r0 = (rem & 31) * 32, c0 = (rem >> 5) * 32;  // r over D(=k), c over E(=n)
    #pragma unroll
    for (int kq = 0; kq < 4; kq++)
      tile[ty + 8*kq][tx] = ib[(size_t)(r0 + ty + 8*kq) * Ee + (c0 + tx)];
    __syncthreads();
    const int k = r0 + tx;
    #pragma unroll
    for (int kq = 0; kq < 4; kq++) {
      const int n = c0 + ty + 8*kq;
      ob[(((size_t)(k >> 3) * 128 + n) << 3) + (k & 7)] = f2h(tile[tx][ty + 8*kq]);
    }
  } else {
    const int idx = bid - (4096 + 3072);
    const int r0 = (idx & 31) * 32, c0 = (idx >> 5) * 32;  // r over h*E(=k), c over D(=n)
    const int C = Dd;
    #pragma unroll
    for (int kq = 0; kq < 4; kq++)
      tile[ty + 8*kq][tx] = Wo[(size_t)(r0 + ty + 8*kq) * C + (c0 + tx)];
    __syncthreads();
    const int k = r0 + tx;
    #pragma unroll
    for (int kq = 0; kq < 4; kq++) {
      const int n = c0 + ty + 8*kq;
      woT[(size_t)(n >> 7) * 131072 +
          (((size_t)(k >> 3) * 128 + (n & 127)) << 3) + (k & 7)] = f2h(tile[tx][ty + 8*kq]);
    }
  }
}

// ---------------- GEMM core: MTx128 tile, BK=64, 4 waves, 16x16x32 f16 MFMA ----------------
// A: [M][K] f16 row-major -> global_load_lds into XOR-swizzled LDS, DOUBLE-BUFFERED:
//    stage A(w+1) into buf^1 while MFMAs consume buf^0; ONE barrier per iteration.
//    Swizzle: chunk p = row*8 + pc holds A[row][((pc ^ (row&7))*8) .. +7] (conflicts=0, R5).
// B: fragment-major global [kc][n(128)][8] — per-lane b128 loads straight to VGPRs
//    (L2-resident), register-double-buffered one iteration ahead.
// R8: K-window loop unrolled x2 with explicit even/odd phases so the B register
//    double-buffer needs NO per-iteration copy chain (was 32 v_mov/iter), and half
//    the addressing folds to immediates. Barrier semantics identical to R7.
// As points to 2*MT*64 u16 of LDS (two buffers).
template<int MT>   // 128 or 64
__device__ __forceinline__ void gemm_core(
    const u16* __restrict__ A, const u16* __restrict__ Btf,
    u16* As, f32x4 (&acc)[MT / 32][4]) {
  constexpr int MI = MT / 32;
  const int tid = threadIdx.x;
  const int wave = tid >> 6;
  const int lane = tid & 63;
  // lane l -> row +(l>>3), chunk col pc = l&7, logical col lc = pc ^ (l>>3)
  const size_t lnoff = (size_t)(lane >> 3) * Kk + (size_t)(((lane & 7) ^ (lane >> 3)) * 8);

  const int wm = (wave >> 1) * (MT / 2);  // wave 2x2 arrangement
  const int wn = (wave & 1) * 64;
  const int fr = lane & 15;            // A: m-in-16 / B: n-in-16
  const int q  = lane >> 4;            // k quad: holds k = kwin*32 + q*8 .. +7
  const int sw = fr & 7;               // row-swizzle for A frag reads

  // per-lane A global base pointers, hoisted
  const u16* agp[MI];
  #pragma unroll
  for (int c = 0; c < MI; c++)
    agp[c] = A + lnoff + (size_t)((c * 4 + wave) * 8) * Kk;

  // B frag pointer: elem offset kc*1024 + n*8, kc = kt/8 + ks*4 + q (q folded in)
  const u16* bptr = Btf + ((size_t)q * 128 + wn + fr) * 8;
  f16x8 b0[8], b1[8];
  #pragma unroll
  for (int ks = 0; ks < 2; ks++)
    #pragma unroll
    for (int j = 0; j < 4; j++)
      b0[ks * 4 + j] = *(const f16x8*)(bptr + (ks * 4) * 1024 + j * 128);

  #pragma unroll
  for (int i = 0; i < MI; i++)
    #pragma unroll
    for (int j = 0; j < 4; j++)
      #pragma unroll
      for (int r = 0; r < 4; r++) acc[i][j][r] = 0.0f;

  // prologue: stage window 0 into buf0 (latency exposed once)
  #pragma unroll
  for (int c = 0; c < MI; c++)
    gll16(agp[c], As + (c * 4 + wave) * 512);
  __syncthreads();

  u16* const buf0 = As;
  u16* const buf1 = As + MT * 64;

  auto phase = [&](int w, u16* cur, u16* nxt, f16x8 (&bc)[8], f16x8 (&bn)[8]) {
    const int kt = w * 64;
    // stage next A window (overlaps with compute below; drained at phase-end barrier)
    if (w + 1 < Kk / 64) {
      #pragma unroll
      for (int c = 0; c < MI; c++)
        gll16(agp[c] + kt + 64, nxt + (c * 4 + wave) * 512);
    }
    // prefetch next B window into regs (wrap on last iter; values unused)
    const int ktn = (kt + 64) & (Kk - 1);
    #pragma unroll
    for (int ks = 0; ks < 2; ks++)
      #pragma unroll
      for (int j = 0; j < 4; j++)
        bn[ks * 4 + j] = *(const f16x8*)(bptr + ((ktn >> 3) + ks * 4) * 1024 + j * 128);
    // compute current window
    #pragma unroll
    for (int ks = 0; ks < 2; ks++) {
      const int col = ((ks << 2) | q) ^ sw;   // phys 16B-chunk column (A swizzle)
      f16x8 ah[MI];
      #pragma unroll
      for (int i = 0; i < MI; i++)
        ah[i] = *(const f16x8*)(cur + (wm + i * 16 + fr) * 64 + col * 8);
      #pragma unroll
      for (int i = 0; i < MI; i++)
        #pragma unroll
        for (int j = 0; j < 4; j++)
          acc[i][j] = __builtin_amdgcn_mfma_f32_16x16x32_f16(ah[i], bc[ks * 4 + j], acc[i][j], 0, 0, 0);
    }
    __syncthreads();   // my ds_reads of cur done; all waves' stage of nxt drained
  };

  for (int w = 0; w < Kk / 64; w += 2) {
    phase(w,     buf0, buf1, b0, b1);
    phase(w + 1, buf1, buf0, b1, b0);
  }
}

// C/D layout (measured m89/m91): col = lane&15, row = (lane>>4)*4 + reg

__global__ __launch_bounds__(256) void gemm_qkv(
    const u16* __restrict__ xh, const u16* __restrict__ wT,
    const float* __restrict__ bq, const float* __restrict__ bk, const float* __restrict__ bv,
    u16* __restrict__ q, u16* __restrict__ k, u16* __restrict__ v) {
  __shared__ u16 As[128 * 64 * 2];
  const int m0 = blockIdx.x * 128;
  const int z = blockIdx.z;            // proj*8 + h
  const int proj = z >> 3, h = z & 7;
  f32x4 acc[4][4];
  gemm_core<128>(xh + (size_t)m0 * Kk, wT + (size_t)z * (Ee * Kk), As, acc);

  u16* dst = proj == 0 ? q : (proj == 1 ? k : v);
  const float* bias = proj == 0 ? bq : (proj == 1 ? bk : bv);
  const int wave = threadIdx.x >> 6, lane = threadIdx.x & 63;
  const int wm = (wave >> 1) * 64, wn = (wave & 1) * 64;
  const int cn = lane & 15, rq4 = (lane >> 4) * 4;
  #pragma unroll
  for (int j = 0; j < 4; j++) {
    const int e = wn + j * 16 + cn;
    const float bb = bias[h * Ee + e];
    #pragma unroll
    for (int i = 0; i < 4; i++) {
      #pragma unroll
      for (int r = 0; r < 4; r++) {
        const int m = m0 + wm + i * 16 + rq4 + r;     // m = b*S + s
        const int b = m >> 11, s = m & (Ss - 1);
        dst[(((size_t)(b * Hh + h)) * Ss + s) * Ee + e] = f2h(acc[i][j][r] + bb);
      }
    }
  }
}

__global__ __launch_bounds__(256) void gemm_out(
    const u16* __restrict__ attn, const u16* __restrict__ woT,
    const float* __restrict__ bo, float* __restrict__ out) {
  __shared__ u16 As[64 * 64 * 2];
  const int m0 = blockIdx.x * 64;
  const int n0 = blockIdx.y * 128;
  f32x4 acc[2][4];
  gemm_core<64>(attn + (size_t)m0 * Kk, woT + (size_t)blockIdx.y * 131072, As, acc);
  const int wave = threadIdx.x >> 6, lane = threadIdx.x & 63;
  const int wm = (wave >> 1) * 32, wn = (wave & 1) * 64;
  const int cn = lane & 15, rq4 = (lane >> 4) * 4;
  #pragma unroll
  for (int j = 0; j < 4; j++) {
    const int n = n0 + wn + j * 16 + cn;
    const float bb = bo[n];
    #pragma unroll
    for (int i = 0; i < 2; i++) {
      #pragma unroll
      for (int r = 0; r < 4; r++) {
        const int m = m0 + wm + i * 16 + rq4 + r;
        out[(size_t)m * Dd + n] = acc[i][j][r] + bb;
      }
    }
  }
}

// ---------------- attention: 4 s per wave (16-lane groups), dwordx4 loads ----------------
// Each wave = four 16-lane groups, one (b,h,s) each; lane lx owns elements
// e0 = lx*8 .. +7 (16B dwordx4 per row). All shuffle masks < 16, so every
// wave-wide shuffle serves all 4 groups at once: reduce-scatter (15 sh) lands
// logit j = lx on lane lx (no replication), max/sum all-reduce (8 sh), allgather
// g[t] = w[lx^t] (15 sh). V rows preloaded in lx^t order (compile-time register
// indices) so their L2 latency hides under the 38-shuffle chain.
// R8: logit phase uses packed-f16 fdot2 (q never unpacked to f32): 4 fdot2 per
// j replaces 8 cvt + 8 fma.
__global__ __launch_bounds__(256) void attn_kernel(
    const u16* __restrict__ q, const u16* __restrict__ k, const u16* __restrict__ v,
    const float* __restrict__ bk, const float* __restrict__ bv,
    const int* __restrict__ dil, u16* __restrict__ attn) {
  // XCD-contiguous swizzle: XCD i (= blockIdx%8 round-robin) gets a contiguous
  // blk range = 2 whole (b,h) panels -> disjoint ~3MB L2 working set per XCD.
  const int nblk = (Bb * Hh * Ss) / 16;           // 2048 blocks, 4 waves x 4 s
  const int blk = (blockIdx.x & 7) * (nblk / 8) + (blockIdx.x >> 3);
  const int wid = blk * 4 + (threadIdx.x >> 6);   // [0, 8192)
  const int lane = threadIdx.x & 63;
  const int grp = lane >> 4;                       // which s of this wave's 4
  const int lx = lane & 15;                        // lane within 16-group
  const int idx = wid * 4 + grp;                   // global (b,h,s) task
  const int s = idx & (Ss - 1);
  const int bh = idx >> 11;                        // b*H + h
  const int h = bh & 7, b = bh >> 3;
  const int d = dil[h];
  const size_t base = (size_t)bh * Ss * Ee;        // u16 elements
  const u16* kp = k + base;
  const u16* vp = v + base;
  const int e0 = lx * 8;
  const int off = (d * (KWW - 1)) >> 1;

  // q slice, kept packed f16 for fdot2
  h2 qh[4];
  {
    uint4 qw = *(const uint4*)(q + base + (size_t)s * Ee + e0);
    qh[0] = as_h2(qw.x); qh[1] = as_h2(qw.y); qh[2] = as_h2(qw.z); qh[3] = as_h2(qw.w);
  }
  // bias slices (padded key/value = bias projection of zero-embedding)
  h2 bkh[4];
  float bvf[8];
  {
    const float4 a0 = ((const float4*)(bk + h * Ee + e0))[0];
    const float4 a1 = ((const float4*)(bk + h * Ee + e0))[1];
    bkh[0] = mk_h2(a0.x, a0.y); bkh[1] = mk_h2(a0.z, a0.w);
    bkh[2] = mk_h2(a1.x, a1.y); bkh[3] = mk_h2(a1.z, a1.w);
    const float4 c0 = ((const float4*)(bv + h * Ee + e0))[0];
    const float4 c1 = ((const float4*)(bv + h * Ee + e0))[1];
    bvf[0]=c0.x; bvf[1]=c0.y; bvf[2]=c0.z; bvf[3]=c0.w;
    bvf[4]=c1.x; bvf[5]=c1.y; bvf[6]=c1.z; bvf[7]=c1.w;
  }
  float blog;
  {
    float t = __builtin_amdgcn_fdot2(qh[0], bkh[0], 0.0f, false);
    t = __builtin_amdgcn_fdot2(qh[1], bkh[1], t, false);
    t = __builtin_amdgcn_fdot2(qh[2], bkh[2], t, false);
    blog = __builtin_amdgcn_fdot2(qh[3], bkh[3], t, false);
  }
  // packed f16 v-bias for OOB substitution at load time
  uint4 bvh;
  bvh.x = (uint32_t)f2h(bvf[0]) | ((uint32_t)f2h(bvf[1]) << 16);
  bvh.y = (uint32_t)f2h(bvf[2]) | ((uint32_t)f2h(bvf[3]) << 16);
  bvh.z = (uint32_t)f2h(bvf[4]) | ((uint32_t)f2h(bvf[5]) << 16);
  bvh.w = (uint32_t)f2h(bvf[6]) | ((uint32_t)f2h(bvf[7]) << 16);

  // ---- logit partials: lane lx holds partial (over its 8 elems) for ALL 16 j ----
  float logit[KWW];
  #pragma unroll
  for (int j = 0; j < KWW; j++) {
    const int pos = s + d * j - off;
    const int posc = min(max(pos, 0), Ss - 1);
    uint4 kw = *(const uint4*)(kp + (size_t)posc * Ee + e0);
    float t = __builtin_amdgcn_fdot2(qh[0], as_h2(kw.x), 0.0f, false);
    t = __builtin_amdgcn_fdot2(qh[1], as_h2(kw.y), t, false);
    t = __builtin_amdgcn_fdot2(qh[2], as_h2(kw.z), t, false);
    t = __builtin_amdgcn_fdot2(qh[3], as_h2(kw.w), t, false);
    logit[j] = (pos >= 0 && pos < Ss) ? t : blog;
  }

  // ---- preload v rows in j = lx^t order (OOB -> bias, selected on dwords) ----
  uint4 vrow[KWW];
  #pragma unroll
  for (int t = 0; t < KWW; t++) {
    const int j = lx ^ t;
    const int pos = s + d * j - off;
    const int posc = min(max(pos, 0), Ss - 1);
    uint4 vw = *(const uint4*)(vp + (size_t)posc * Ee + e0);
    const bool ok = (pos >= 0) && (pos < Ss);
    vrow[t].x = ok ? vw.x : bvh.x;
    vrow[t].y = ok ? vw.y : bvh.y;
    vrow[t].z = ok ? vw.z : bvh.z;
    vrow[t].w = ok ? vw.w : bvh.w;
  }

  // ---- reduce-scatter within 16-lane groups: lane lx ends owning logit j = lx ----
  {
    const bool hi = (lx & 8) != 0;
    #pragma unroll
    for (int jj = 0; jj < 8; jj++) {
      float send = hi ? logit[jj] : logit[jj + 8];
      float recv = __shfl_xor(send, 8, 64);
      logit[jj] = (hi ? logit[jj + 8] : logit[jj]) + recv;
    }
  }
  {
    const bool hi = (lx & 4) != 0;
    #pragma unroll
    for (int jj = 0; jj < 4; jj++) {
      float send = hi ? logit[jj] : logit[jj + 4];
      float recv = __shfl_xor(send, 4, 64);
      logit[jj] = (hi ? logit[jj + 4] : logit[jj]) + recv;
    }
  }
  {
    const bool hi = (lx & 2) != 0;
    #pragma unroll
    for (int jj = 0; jj < 2; jj++) {
      float send = hi ? logit[jj] : logit[jj + 2];
      float recv = __shfl_xor(send, 2, 64);
      logit[jj] = (hi ? logit[jj + 2] : logit[jj]) + recv;
    }
  }
  float own;
  {
    const bool hi = (lx & 1) != 0;
    float send = hi ? logit[0] : logit[1];
    float recv = __shfl_xor(send, 1, 64);
    own = (hi ? logit[1] : logit[0]) + recv;   // own = full logit for j = lx
  }

  // ---- softmax over the 16 j's (one per lane in the group) ----
  float mx = own;
  mx = fmaxf(mx, __shfl_xor(mx, 1, 64));
  mx = fmaxf(mx, __shfl_xor(mx, 2, 64));
  mx = fmaxf(mx, __shfl_xor(mx, 4, 64));
  mx = fmaxf(mx, __shfl_xor(mx, 8, 64));
  float w = __expf(own - mx);
  float sum = w;
  sum += __shfl_xor(sum, 1, 64);
  sum += __shfl_xor(sum, 2, 64);
  sum += __shfl_xor(sum, 4, 64);
  sum += __shfl_xor(sum, 8, 64);
  w *= 1.0f / (sum * 11.313708498984760f);  // /Z /sqrt(E), post-softmax quirk

  // ---- allgather within group: g[t] = w[lx ^ t] ----
  float g[KWW];
  g[0] = w;
  g[1] = __shfl_xor(g[0], 1, 64);
  #pragma unroll
  for (int t = 0; t < 2; t++) g[2 + t] = __shfl_xor(g[t], 2, 64);
  #pragma unroll
  for (int t = 0; t < 4; t++) g[4 + t] = __shfl_xor(g[t], 4, 64);
  #pragma unroll
  for (int t = 0; t < 8; t++) g[8 + t] = __shfl_xor(g[t], 8, 64);

  // ---- PV: acc_e = sum_t g[t] * v[lx^t][e] ----
  float acc[8];
  #pragma unroll
  for (int i = 0; i < 8; i++) acc[i] = 0.f;
  #pragma unroll
  for (int t = 0; t < KWW; t++) {
    const float wt = g[t];
    acc[0] += wt * h2f_lo(vrow[t].x);
    acc[1] += wt * h2f_hi(vrow[t].x);
    acc[2] += wt * h2f_lo(vrow[t].y);
    acc[3] += wt * h2f_hi(vrow[t].y);
    acc[4] += wt * h2f_lo(vrow[t].z);
    acc[5] += wt * h2f_hi(vrow[t].z);
    acc[6] += wt * h2f_lo(vrow[t].w);
    acc[7] += wt * h2f_hi(vrow[t].w);
  }

  // write fp16 attn as A-matrix [b*S+s][h*E+e], 16B per lane (coalesced per group)
  uint4 o;
  o.x = (uint32_t)f2h(acc[0]) | ((uint32_t)f2h(acc[1]) << 16);
  o.y = (uint32_t)f2h(acc[2]) | ((uint32_t)f2h(acc[3]) << 16);
  o.z = (uint32_t)f2h(acc[4]) | ((uint32_t)f2h(acc[5]) << 16);
  o.w = (uint32_t)f2h(acc[6]) | ((uint32_t)f2h(acc[7]) << 16);
  *(uint4*)(attn + (size_t)(b * Ss + s) * (Hh * Ee) + h * Ee + e0) = o;
}

// ---------------- launcher ----------------
extern "C" void kernel_launch(void* const* d_in, const int* in_sizes, int n_in,
                              void* d_out, int out_size, void* d_ws, size_t ws_size,
                              hipStream_t stream) {
  (void)in_sizes; (void)n_in; (void)out_size; (void)ws_size;
  const float* x  = (const float*)d_in[0];
  const float* Wq = (const float*)d_in[1];
  const float* bq = (const float*)d_in[2];
  const float* Wk = (const float*)d_in[3];
  const float* bk = (const float*)d_in[4];
  const float* Wv = (const float*)d_in[5];
  const float* bv = (const float*)d_in[6];
  const float* Wo = (const float*)d_in[7];
  const float* bo = (const float*)d_in[8];
  const int* dil  = (const int*)d_in[9];
  float* out = (float*)d_out;

  char* ws = (char*)d_ws;
  u16* xh  = (u16*)ws;  ws += (size_t)Mm * Kk * 2;             // 8 MB  [m][d] f16
  u16* wT  = (u16*)ws;  ws += (size_t)24 * Ee * Kk * 2;        // 6 MB  frag-major [z][kc][n][8]
  u16* woT = (u16*)ws;  ws += (size_t)Kk * Dd * 2;             // 2 MB  frag-major [nb][kc][nn][8]
  u16* q = (u16*)ws; ws += (size_t)Bb * Hh * Ss * Ee * 2;      // 8 MB each, f16 [bh][s][e]
  u16* k = (u16*)ws; ws += (size_t)Bb * Hh * Ss * Ee * 2;
  u16* v = (u16*)ws; ws += (size_t)Bb * Hh * Ss * Ee * 2;
  // attn (8 MB f16) aliases xh — dead after gemm_qkv (stream-ordered)
  u16* attn = xh;

  prep<<<8192, 256, 0, stream>>>(x, Wq, Wk, Wv, Wo, xh, wT, woT);
  gemm_qkv<<<dim3(Mm / 128, 1, 24), 256, 0, stream>>>(xh, wT, bq, bk, bv, q, k, v);
  attn_kernel<<<(Bb * Hh * Ss) / 16, 256, 0, stream>>>(q, k, v, bk, bv, dil, attn);
  gemm_out<<<dim3(Mm / 64, Dd / 128), 256, 0, stream>>>(attn, woT, bo, out);
}

// Round 3
// 160.792 us; speedup vs baseline: 1.0328x; 1.0328x over previous
//
#include <hip/hip_runtime.h>
#include <stdint.h>

#define Bb 2
#define Ss 2048
#define Dd 1024
#define Hh 8
#define Ee 128
#define KWW 16
#define Mm (Bb*Ss)   // 4096
#define Kk 1024      // K for both GEMMs

typedef unsigned short u16;
typedef __attribute__((ext_vector_type(8))) _Float16 f16x8;  // 8 fp16 (4 VGPRs)
typedef __attribute__((ext_vector_type(4))) float f32x4;

// fp32 -> fp16 (RTN)
__device__ __forceinline__ u16 f2h(float f) {
  union { _Float16 h; u16 u; } v; v.h = (_Float16)f; return v.u;
}
__device__ __forceinline__ float h2f(u16 u) {
  union { u16 u; _Float16 h; } v; v.u = u; return (float)v.h;
}
__device__ __forceinline__ float h2f_lo(uint32_t w) { return h2f((u16)(w & 0xFFFF)); }
__device__ __forceinline__ float h2f_hi(uint32_t w) { return h2f((u16)(w >> 16)); }

// async global->LDS, 16B per lane. LDS dst must be wave-uniform base; HW scatters lane*16B.
__device__ __forceinline__ void gll16(const void* g, void* l) {
  __builtin_amdgcn_global_load_lds((const __attribute__((address_space(1))) void*)g,
                                   (__attribute__((address_space(3))) void*)l, 16, 0, 0);
}

// ---------------- fused prep kernel ----------------
// Weights are emitted FRAGMENT-MAJOR: [kc][n][8] per panel (kc = k/8), so the
// GEMM B-operand is loaded straight from global as per-lane b128 (no LDS for B).
// blocks [0,4096): cast x f32->f16
// blocks [4096,7168): Wq/Wk/Wv [h][D][E] -> wT[z][kc][n(E)][8], z=proj*8+h
// blocks [7168,8192): Wo [h*E][D] -> woT[nb][kc][nn][8], n = nb*128+nn over D
__global__ __launch_bounds__(256) void prep(
    const float* __restrict__ x, const float* __restrict__ Wq,
    const float* __restrict__ Wk, const float* __restrict__ Wv,
    const float* __restrict__ Wo,
    u16* __restrict__ xh, u16* __restrict__ wT, u16* __restrict__ woT) {
  const int bid = blockIdx.x;
  const int tid = threadIdx.x;
  if (bid < 4096) {
    int i = (bid * 256 + tid) * 4;
    float4 f = *(const float4*)(x + i);
    uint64_t pk = (uint64_t)f2h(f.x) | ((uint64_t)f2h(f.y) << 16) |
                  ((uint64_t)f2h(f.z) << 32) | ((uint64_t)f2h(f.w) << 48);
    *(uint64_t*)(xh + i) = pk;
    return;
  }
  __shared__ float tile[32][33];  // +1 pad: bank-conflict-free
  const int tx = tid & 31, ty = tid >> 5;  // (32,8) shape
  if (bid < 4096 + 3072) {
    const int idx = bid - 4096;
    const int z = idx >> 7, rem = idx & 127;
    const int h = z & 7;
    const float* W = (z < 8) ? Wq : (z < 16) ? Wk : Wv;
    const float* ib = W + (size_t)h * Dd * Ee;
    u16* ob = wT + (size_t)z * Ee * Kk;   // 131072 elems = [kc 128][n 128][8]
    const int r0 = (rem & 31) * 32, c0 = (rem >> 5) * 32;  // r over D(=k), c over E(=n)
    #pragma unroll
    for (int kq = 0; kq < 4; kq++)
      tile[ty + 8*kq][tx] = ib[(size_t)(r0 + ty + 8*kq) * Ee + (c0 + tx)];
    __syncthreads();
    const int k = r0 + tx;
    #pragma unroll
    for (int kq = 0; kq < 4; kq++) {
      const int n = c0 + ty + 8*kq;
      ob[(((size_t)(k >> 3) * 128 + n) << 3) + (k & 7)] = f2h(tile[tx][ty + 8*kq]);
    }
  } else {
    const int idx = bid - (4096 + 3072);
    const int r0 = (idx & 31) * 32, c0 = (idx >> 5) * 32;  // r over h*E(=k), c over D(=n)
    const int C = Dd;
    #pragma unroll
    for (int kq = 0; kq < 4; kq++)
      tile[ty + 8*kq][tx] = Wo[(size_t)(r0 + ty + 8*kq) * C + (c0 + tx)];
    __syncthreads();
    const int k = r0 + tx;
    #pragma unroll
    for (int kq = 0; kq < 4; kq++) {
      const int n = c0 + ty + 8*kq;
      woT[(size_t)(n >> 7) * 131072 +
          (((size_t)(k >> 3) * 128 + (n & 127)) << 3) + (k & 7)] = f2h(tile[tx][ty + 8*kq]);
    }
  }
}

// ---------------- GEMM core: MTx128 tile, BK=64, 4 waves, 16x16x32 f16 MFMA ----------------
// A: [M][K] f16 row-major -> global_load_lds into XOR-swizzled LDS, DOUBLE-BUFFERED:
//    stage A(w+1) into buf^1 while MFMAs consume buf^0; ONE barrier per iteration,
//    so the vmcnt(0) drain at the barrier covers loads that had a full compute
//    phase to land (R7: exposed staging latency was the 2400cyc/iter critical path).
//    Swizzle: chunk p = row*8 + pc holds A[row][((pc ^ (row&7))*8) .. +7] (conflicts=0, R5).
// B: fragment-major global [kc][n(128)][8] — per-lane b128 loads straight to VGPRs
//    (L2-resident), register-double-buffered one iteration ahead.
// R9: K-window loop FULLY UNROLLED (16 iters): every kt/ktn folds to a literal
//    (B-load offsets become immediates) and register renaming across iterations
//    eliminates the 32-mov bcur<-bnxt copy chain. Loop body and barrier
//    semantics otherwise IDENTICAL to the R7 structure (158.5us).
// As points to 2*MT*64 u16 of LDS (two buffers).
template<int MT>   // 128 or 64
__device__ __forceinline__ void gemm_core(
    const u16* __restrict__ A, const u16* __restrict__ Btf,
    u16* As, f32x4 (&acc)[MT / 32][4]) {
  constexpr int MI = MT / 32;
  const int tid = threadIdx.x;
  const int wave = tid >> 6;
  const int lane = tid & 63;
  // lane l -> row +(l>>3), chunk col pc = l&7, logical col lc = pc ^ (l>>3)
  const size_t lnoff = (size_t)(lane >> 3) * Kk + (size_t)(((lane & 7) ^ (lane >> 3)) * 8);

  const int wm = (wave >> 1) * (MT / 2);  // wave 2x2 arrangement
  const int wn = (wave & 1) * 64;
  const int fr = lane & 15;            // A: m-in-16 / B: n-in-16
  const int q  = lane >> 4;            // k quad: holds k = kwin*32 + q*8 .. +7
  const int sw = fr & 7;               // row-swizzle for A frag reads

  // B frag pointer: elem offset kc*1024 + n*8, kc = kt/8 + ks*4 + q (q folded in)
  const u16* bptr = Btf + ((size_t)q * 128 + wn + fr) * 8;
  f16x8 bcur[8], bnxt[8];
  #pragma unroll
  for (int ks = 0; ks < 2; ks++)
    #pragma unroll
    for (int j = 0; j < 4; j++)
      bcur[ks * 4 + j] = *(const f16x8*)(bptr + (ks * 4) * 1024 + j * 128);

  #pragma unroll
  for (int i = 0; i < MI; i++)
    #pragma unroll
    for (int j = 0; j < 4; j++)
      #pragma unroll
      for (int r = 0; r < 4; r++) acc[i][j][r] = 0.0f;

  // prologue: stage window 0 into buf0 (latency exposed once)
  #pragma unroll
  for (int c = 0; c < MI; c++)
    gll16(A + lnoff + (size_t)((c * 4 + wave) * 8) * Kk, As + (c * 4 + wave) * 512);
  __syncthreads();

  #pragma unroll
  for (int w = 0; w < Kk / 64; w++) {
    const int kt = w * 64;
    u16* cur = As + (w & 1) * (MT * 64);
    u16* nxt = As + ((w + 1) & 1) * (MT * 64);
    // stage next A window (overlaps with compute below; drained at loop-end barrier)
    if (w + 1 < Kk / 64) {
      #pragma unroll
      for (int c = 0; c < MI; c++)
        gll16(A + lnoff + (size_t)((c * 4 + wave) * 8) * Kk + kt + 64, nxt + (c * 4 + wave) * 512);
    }
    // prefetch next B window into regs (wrap on last iter; values unused)
    const int ktn = (kt + 64) & (Kk - 1);
    #pragma unroll
    for (int ks = 0; ks < 2; ks++)
      #pragma unroll
      for (int j = 0; j < 4; j++)
        bnxt[ks * 4 + j] = *(const f16x8*)(bptr + ((ktn >> 3) + ks * 4) * 1024 + j * 128);
    // compute current window
    #pragma unroll
    for (int ks = 0; ks < 2; ks++) {
      const int col = ((ks << 2) | q) ^ sw;   // phys 16B-chunk column (A swizzle)
      f16x8 ah[MI];
      #pragma unroll
      for (int i = 0; i < MI; i++)
        ah[i] = *(const f16x8*)(cur + (wm + i * 16 + fr) * 64 + col * 8);
      #pragma unroll
      for (int i = 0; i < MI; i++)
        #pragma unroll
        for (int j = 0; j < 4; j++)
          acc[i][j] = __builtin_amdgcn_mfma_f32_16x16x32_f16(ah[i], bcur[ks * 4 + j], acc[i][j], 0, 0, 0);
    }
    __syncthreads();   // single barrier: my ds_reads of cur done; all waves' stage of nxt drained
    #pragma unroll
    for (int t = 0; t < 8; t++) bcur[t] = bnxt[t];
  }
}

// C/D layout (measured m89/m91): col = lane&15, row = (lane>>4)*4 + reg

__global__ __launch_bounds__(256) void gemm_qkv(
    const u16* __restrict__ xh, const u16* __restrict__ wT,
    const float* __restrict__ bq, const float* __restrict__ bk, const float* __restrict__ bv,
    u16* __restrict__ q, u16* __restrict__ k, u16* __restrict__ v) {
  __shared__ u16 As[128 * 64 * 2];
  const int m0 = blockIdx.x * 128;
  const int z = blockIdx.z;            // proj*8 + h
  const int proj = z >> 3, h = z & 7;
  f32x4 acc[4][4];
  gemm_core<128>(xh + (size_t)m0 * Kk, wT + (size_t)z * (Ee * Kk), As, acc);

  u16* dst = proj == 0 ? q : (proj == 1 ? k : v);
  const float* bias = proj == 0 ? bq : (proj == 1 ? bk : bv);
  const int wave = threadIdx.x >> 6, lane = threadIdx.x & 63;
  const int wm = (wave >> 1) * 64, wn = (wave & 1) * 64;
  const int cn = lane & 15, rq4 = (lane >> 4) * 4;
  #pragma unroll
  for (int j = 0; j < 4; j++) {
    const int e = wn + j * 16 + cn;
    const float bb = bias[h * Ee + e];
    #pragma unroll
    for (int i = 0; i < 4; i++) {
      #pragma unroll
      for (int r = 0; r < 4; r++) {
        const int m = m0 + wm + i * 16 + rq4 + r;     // m = b*S + s
        const int b = m >> 11, s = m & (Ss - 1);
        dst[(((size_t)(b * Hh + h)) * Ss + s) * Ee + e] = f2h(acc[i][j][r] + bb);
      }
    }
  }
}

__global__ __launch_bounds__(256) void gemm_out(
    const u16* __restrict__ attn, const u16* __restrict__ woT,
    const float* __restrict__ bo, float* __restrict__ out) {
  __shared__ u16 As[64 * 64 * 2];
  const int m0 = blockIdx.x * 64;
  const int n0 = blockIdx.y * 128;
  f32x4 acc[2][4];
  gemm_core<64>(attn + (size_t)m0 * Kk, woT + (size_t)blockIdx.y * 131072, As, acc);
  const int wave = threadIdx.x >> 6, lane = threadIdx.x & 63;
  const int wm = (wave >> 1) * 32, wn = (wave & 1) * 64;
  const int cn = lane & 15, rq4 = (lane >> 4) * 4;
  #pragma unroll
  for (int j = 0; j < 4; j++) {
    const int n = n0 + wn + j * 16 + cn;
    const float bb = bo[n];
    #pragma unroll
    for (int i = 0; i < 2; i++) {
      #pragma unroll
      for (int r = 0; r < 4; r++) {
        const int m = m0 + wm + i * 16 + rq4 + r;
        out[(size_t)m * Dd + n] = acc[i][j][r] + bb;
      }
    }
  }
}

// ---------------- attention: 4 s per wave (16-lane groups), dwordx4 loads ----------------
// Each wave = four 16-lane groups, one (b,h,s) each; lane lx owns elements
// e0 = lx*8 .. +7 (16B dwordx4 per row). All shuffle masks < 16, so every
// wave-wide shuffle serves all 4 groups at once: reduce-scatter (15 sh) lands
// logit j = lx on lane lx (no replication), max/sum all-reduce (8 sh), allgather
// g[t] = w[lx^t] (15 sh). V rows preloaded in lx^t order (compile-time register
// indices) so their L2 latency hides under the 38-shuffle chain.
__global__ __launch_bounds__(256) void attn_kernel(
    const u16* __restrict__ q, const u16* __restrict__ k, const u16* __restrict__ v,
    const float* __restrict__ bk, const float* __restrict__ bv,
    const int* __restrict__ dil, u16* __restrict__ attn) {
  // XCD-contiguous swizzle: XCD i (= blockIdx%8 round-robin) gets a contiguous
  // blk range = 2 whole (b,h) panels -> disjoint ~3MB L2 working set per XCD.
  const int nblk = (Bb * Hh * Ss) / 16;           // 2048 blocks, 4 waves x 4 s
  const int blk = (blockIdx.x & 7) * (nblk / 8) + (blockIdx.x >> 3);
  const int wid = blk * 4 + (threadIdx.x >> 6);   // [0, 8192)
  const int lane = threadIdx.x & 63;
  const int grp = lane >> 4;                       // which s of this wave's 4
  const int lx = lane & 15;                        // lane within 16-group
  const int idx = wid * 4 + grp;                   // global (b,h,s) task
  const int s = idx & (Ss - 1);
  const int bh = idx >> 11;                        // b*H + h
  const int h = bh & 7, b = bh >> 3;
  const int d = dil[h];
  const size_t base = (size_t)bh * Ss * Ee;        // u16 elements
  const u16* kp = k + base;
  const u16* vp = v + base;
  const int e0 = lx * 8;
  const int off = (d * (KWW - 1)) >> 1;

  // q slice -> f32
  float qf[8];
  {
    uint4 qw = *(const uint4*)(q + base + (size_t)s * Ee + e0);
    qf[0] = h2f_lo(qw.x); qf[1] = h2f_hi(qw.x);
    qf[2] = h2f_lo(qw.y); qf[3] = h2f_hi(qw.y);
    qf[4] = h2f_lo(qw.z); qf[5] = h2f_hi(qw.z);
    qf[6] = h2f_lo(qw.w); qf[7] = h2f_hi(qw.w);
  }
  // bias slices (padded key/value = bias projection of zero-embedding)
  float bkf[8], bvf[8];
  {
    const float4 a0 = ((const float4*)(bk + h * Ee + e0))[0];
    const float4 a1 = ((const float4*)(bk + h * Ee + e0))[1];
    bkf[0]=a0.x; bkf[1]=a0.y; bkf[2]=a0.z; bkf[3]=a0.w;
    bkf[4]=a1.x; bkf[5]=a1.y; bkf[6]=a1.z; bkf[7]=a1.w;
    const float4 c0 = ((const float4*)(bv + h * Ee + e0))[0];
    const float4 c1 = ((const float4*)(bv + h * Ee + e0))[1];
    bvf[0]=c0.x; bvf[1]=c0.y; bvf[2]=c0.z; bvf[3]=c0.w;
    bvf[4]=c1.x; bvf[5]=c1.y; bvf[6]=c1.z; bvf[7]=c1.w;
  }
  float blog = 0.f;
  #pragma unroll
  for (int i = 0; i < 8; i++) blog += qf[i] * bkf[i];
  // packed f16 v-bias for OOB substitution at load time
  uint4 bvh;
  bvh.x = (uint32_t)f2h(bvf[0]) | ((uint32_t)f2h(bvf[1]) << 16);
  bvh.y = (uint32_t)f2h(bvf[2]) | ((uint32_t)f2h(bvf[3]) << 16);
  bvh.z = (uint32_t)f2h(bvf[4]) | ((uint32_t)f2h(bvf[5]) << 16);
  bvh.w = (uint32_t)f2h(bvf[6]) | ((uint32_t)f2h(bvf[7]) << 16);

  // ---- logit partials: lane lx holds partial (over its 8 elems) for ALL 16 j ----
  float logit[KWW];
  #pragma unroll
  for (int j = 0; j < KWW; j++) {
    const int pos = s + d * j - off;
    const int posc = min(max(pos, 0), Ss - 1);
    uint4 kw = *(const uint4*)(kp + (size_t)posc * Ee + e0);
    float t = qf[0] * h2f_lo(kw.x) + qf[1] * h2f_hi(kw.x)
            + qf[2] * h2f_lo(kw.y) + qf[3] * h2f_hi(kw.y)
            + qf[4] * h2f_lo(kw.z) + qf[5] * h2f_hi(kw.z)
            + qf[6] * h2f_lo(kw.w) + qf[7] * h2f_hi(kw.w);
    logit[j] = (pos >= 0 && pos < Ss) ? t : blog;
  }

  // ---- preload v rows in j = lx^t order (OOB -> bias, selected on dwords) ----
  uint4 vrow[KWW];
  #pragma unroll
  for (int t = 0; t < KWW; t++) {
    const int j = lx ^ t;
    const int pos = s + d * j - off;
    const int posc = min(max(pos, 0), Ss - 1);
    uint4 vw = *(const uint4*)(vp + (size_t)posc * Ee + e0);
    const bool ok = (pos >= 0) && (pos < Ss);
    vrow[t].x = ok ? vw.x : bvh.x;
    vrow[t].y = ok ? vw.y : bvh.y;
    vrow[t].z = ok ? vw.z : bvh.z;
    vrow[t].w = ok ? vw.w : bvh.w;
  }

  // ---- reduce-scatter within 16-lane groups: lane lx ends owning logit j = lx ----
  {
    const bool hi = (lx & 8) != 0;
    #pragma unroll
    for (int jj = 0; jj < 8; jj++) {
      float send = hi ? logit[jj] : logit[jj + 8];
      float recv = __shfl_xor(send, 8, 64);
      logit[jj] = (hi ? logit[jj + 8] : logit[jj]) + recv;
    }
  }
  {
    const bool hi = (lx & 4) != 0;
    #pragma unroll
    for (int jj = 0; jj < 4; jj++) {
      float send = hi ? logit[jj] : logit[jj + 4];
      float recv = __shfl_xor(send, 4, 64);
      logit[jj] = (hi ? logit[jj + 4] : logit[jj]) + recv;
    }
  }
  {
    const bool hi = (lx & 2) != 0;
    #pragma unroll
    for (int jj = 0; jj < 2; jj++) {
      float send = hi ? logit[jj] : logit[jj + 2];
      float recv = __shfl_xor(send, 2, 64);
      logit[jj] = (hi ? logit[jj + 2] : logit[jj]) + recv;
    }
  }
  float own;
  {
    const bool hi = (lx & 1) != 0;
    float send = hi ? logit[0] : logit[1];
    float recv = __shfl_xor(send, 1, 64);
    own = (hi ? logit[1] : logit[0]) + recv;   // own = full logit for j = lx
  }

  // ---- softmax over the 16 j's (one per lane in the group) ----
  float mx = own;
  mx = fmaxf(mx, __shfl_xor(mx, 1, 64));
  mx = fmaxf(mx, __shfl_xor(mx, 2, 64));
  mx = fmaxf(mx, __shfl_xor(mx, 4, 64));
  mx = fmaxf(mx, __shfl_xor(mx, 8, 64));
  float w = __expf(own - mx);
  float sum = w;
  sum += __shfl_xor(sum, 1, 64);
  sum += __shfl_xor(sum, 2, 64);
  sum += __shfl_xor(sum, 4, 64);
  sum += __shfl_xor(sum, 8, 64);
  w *= 1.0f / (sum * 11.313708498984760f);  // /Z /sqrt(E), post-softmax quirk

  // ---- allgather within group: g[t] = w[lx ^ t] ----
  float g[KWW];
  g[0] = w;
  g[1] = __shfl_xor(g[0], 1, 64);
  #pragma unroll
  for (int t = 0; t < 2; t++) g[2 + t] = __shfl_xor(g[t], 2, 64);
  #pragma unroll
  for (int t = 0; t < 4; t++) g[4 + t] = __shfl_xor(g[t], 4, 64);
  #pragma unroll
  for (int t = 0; t < 8; t++) g[8 + t] = __shfl_xor(g[t], 8, 64);

  // ---- PV: acc_e = sum_t g[t] * v[lx^t][e] ----
  float acc[8];
  #pragma unroll
  for (int i = 0; i < 8; i++) acc[i] = 0.f;
  #pragma unroll
  for (int t = 0; t < KWW; t++) {
    const float wt = g[t];
    acc[0] += wt * h2f_lo(vrow[t].x);
    acc[1] += wt * h2f_hi(vrow[t].x);
    acc[2] += wt * h2f_lo(vrow[t].y);
    acc[3] += wt * h2f_hi(vrow[t].y);
    acc[4] += wt * h2f_lo(vrow[t].z);
    acc[5] += wt * h2f_hi(vrow[t].z);
    acc[6] += wt * h2f_lo(vrow[t].w);
    acc[7] += wt * h2f_hi(vrow[t].w);
  }

  // write fp16 attn as A-matrix [b*S+s][h*E+e], 16B per lane (coalesced per group)
  uint4 o;
  o.x = (uint32_t)f2h(acc[0]) | ((uint32_t)f2h(acc[1]) << 16);
  o.y = (uint32_t)f2h(acc[2]) | ((uint32_t)f2h(acc[3]) << 16);
  o.z = (uint32_t)f2h(acc[4]) | ((uint32_t)f2h(acc[5]) << 16);
  o.w = (uint32_t)f2h(acc[6]) | ((uint32_t)f2h(acc[7]) << 16);
  *(uint4*)(attn + (size_t)(b * Ss + s) * (Hh * Ee) + h * Ee + e0) = o;
}

// ---------------- launcher ----------------
extern "C" void kernel_launch(void* const* d_in, const int* in_sizes, int n_in,
                              void* d_out, int out_size, void* d_ws, size_t ws_size,
                              hipStream_t stream) {
  (void)in_sizes; (void)n_in; (void)out_size; (void)ws_size;
  const float* x  = (const float*)d_in[0];
  const float* Wq = (const float*)d_in[1];
  const float* bq = (const float*)d_in[2];
  const float* Wk = (const float*)d_in[3];
  const float* bk = (const float*)d_in[4];
  const float* Wv = (const float*)d_in[5];
  const float* bv = (const float*)d_in[6];
  const float* Wo = (const float*)d_in[7];
  const float* bo = (const float*)d_in[8];
  const int* dil  = (const int*)d_in[9];
  float* out = (float*)d_out;

  char* ws = (char*)d_ws;
  u16* xh  = (u16*)ws;  ws += (size_t)Mm * Kk * 2;             // 8 MB  [m][d] f16
  u16* wT  = (u16*)ws;  ws += (size_t)24 * Ee * Kk * 2;        // 6 MB  frag-major [z][kc][n][8]
  u16* woT = (u16*)ws;  ws += (size_t)Kk * Dd * 2;             // 2 MB  frag-major [nb][kc][nn][8]
  u16* q = (u16*)ws; ws += (size_t)Bb * Hh * Ss * Ee * 2;      // 8 MB each, f16 [bh][s][e]
  u16* k = (u16*)ws; ws += (size_t)Bb * Hh * Ss * Ee * 2;
  u16* v = (u16*)ws; ws += (size_t)Bb * Hh * Ss * Ee * 2;
  // attn (8 MB f16) aliases xh — dead after gemm_qkv (stream-ordered)
  u16* attn = xh;

  prep<<<8192, 256, 0, stream>>>(x, Wq, Wk, Wv, Wo, xh, wT, woT);
  gemm_qkv<<<dim3(Mm / 128, 1, 24), 256, 0, stream>>>(xh, wT, bq, bk, bv, q, k, v);
  attn_kernel<<<(Bb * Hh * Ss) / 16, 256, 0, stream>>>(q, k, v, bk, bv, dil, attn);
  gemm_out<<<dim3(Mm / 64, Dd / 128), 256, 0, stream>>>(attn, woT, bo, out);
}

// Round 4
// 154.178 us; speedup vs baseline: 1.0771x; 1.0429x over previous
//
#include <hip/hip_runtime.h>
#include <stdint.h>

#define Bb 2
#define Ss 2048
#define Dd 1024
#define Hh 8
#define Ee 128
#define KWW 16
#define Mm (Bb*Ss)   // 4096
#define Kk 1024      // K for both GEMMs

typedef unsigned short u16;
typedef __attribute__((ext_vector_type(8))) _Float16 f16x8;  // 8 fp16 (4 VGPRs)
typedef __attribute__((ext_vector_type(4))) float f32x4;

// fp32 -> fp16 (RTN)
__device__ __forceinline__ u16 f2h(float f) {
  union { _Float16 h; u16 u; } v; v.h = (_Float16)f; return v.u;
}
__device__ __forceinline__ float h2f(u16 u) {
  union { u16 u; _Float16 h; } v; v.u = u; return (float)v.h;
}
__device__ __forceinline__ float h2f_lo(uint32_t w) { return h2f((u16)(w & 0xFFFF)); }
__device__ __forceinline__ float h2f_hi(uint32_t w) { return h2f((u16)(w >> 16)); }

// async global->LDS, 16B per lane. LDS dst must be wave-uniform base; HW scatters lane*16B.
__device__ __forceinline__ void gll16(const void* g, void* l) {
  __builtin_amdgcn_global_load_lds((const __attribute__((address_space(1))) void*)g,
                                   (__attribute__((address_space(3))) void*)l, 16, 0, 0);
}

// ---------------- fused prep kernel ----------------
// Weights are emitted FRAGMENT-MAJOR: [kc][n][8] per panel (kc = k/8), so the
// GEMM B-operand is loaded straight from global as per-lane b128 (no LDS for B).
// blocks [0,4096): cast x f32->f16
// blocks [4096,7168): Wq/Wk/Wv [h][D][E] -> wT[z][kc][n(E)][8], z=proj*8+h
// blocks [7168,8192): Wo [h*E][D] -> woT[nb][kc][nn][8], n = nb*128+nn over D
__global__ __launch_bounds__(256) void prep(
    const float* __restrict__ x, const float* __restrict__ Wq,
    const float* __restrict__ Wk, const float* __restrict__ Wv,
    const float* __restrict__ Wo,
    u16* __restrict__ xh, u16* __restrict__ wT, u16* __restrict__ woT) {
  const int bid = blockIdx.x;
  const int tid = threadIdx.x;
  if (bid < 4096) {
    int i = (bid * 256 + tid) * 4;
    float4 f = *(const float4*)(x + i);
    uint64_t pk = (uint64_t)f2h(f.x) | ((uint64_t)f2h(f.y) << 16) |
                  ((uint64_t)f2h(f.z) << 32) | ((uint64_t)f2h(f.w) << 48);
    *(uint64_t*)(xh + i) = pk;
    return;
  }
  __shared__ float tile[32][33];  // +1 pad: bank-conflict-free
  const int tx = tid & 31, ty = tid >> 5;  // (32,8) shape
  if (bid < 4096 + 3072) {
    const int idx = bid - 4096;
    const int z = idx >> 7, rem = idx & 127;
    const int h = z & 7;
    const float* W = (z < 8) ? Wq : (z < 16) ? Wk : Wv;
    const float* ib = W + (size_t)h * Dd * Ee;
    u16* ob = wT + (size_t)z * Ee * Kk;   // 131072 elems = [kc 128][n 128][8]
    const int r0 = (rem & 31) * 32, c0 = (rem >> 5) * 32;  // r over D(=k), c over E(=n)
    #pragma unroll
    for (int kq = 0; kq < 4; kq++)
      tile[ty + 8*kq][tx] = ib[(size_t)(r0 + ty + 8*kq) * Ee + (c0 + tx)];
    __syncthreads();
    const int k = r0 + tx;
    #pragma unroll
    for (int kq = 0; kq < 4; kq++) {
      const int n = c0 + ty + 8*kq;
      ob[(((size_t)(k >> 3) * 128 + n) << 3) + (k & 7)] = f2h(tile[tx][ty + 8*kq]);
    }
  } else {
    const int idx = bid - (4096 + 3072);
    const int r0 = (idx & 31) * 32, c0 = (idx >> 5) * 32;  // r over h*E(=k), c over D(=n)
    const int C = Dd;
    #pragma unroll
    for (int kq = 0; kq < 4; kq++)
      tile[ty + 8*kq][tx] = Wo[(size_t)(r0 + ty + 8*kq) * C + (c0 + tx)];
    __syncthreads();
    const int k = r0 + tx;
    #pragma unroll
    for (int kq = 0; kq < 4; kq++) {
      const int n = c0 + ty + 8*kq;
      woT[(size_t)(n >> 7) * 131072 +
          (((size_t)(k >> 3) * 128 + (n & 127)) << 3) + (k & 7)] = f2h(tile[tx][ty + 8*kq]);
    }
  }
}

// ---------------- GEMM core: MTx128 tile, BK=64, 4 waves, 16x16x32 f16 MFMA ----------------
// A: [M][K] f16 row-major -> global_load_lds into XOR-swizzled LDS, DOUBLE-BUFFERED:
//    stage A(w+1) into buf^1 while MFMAs consume buf^0; ONE barrier per iteration,
//    so the vmcnt(0) drain at the barrier covers loads that had a full compute
//    phase to land (R7: exposed staging latency was the 2400cyc/iter critical path).
//    Swizzle: chunk p = row*8 + pc holds A[row][((pc ^ (row&7))*8) .. +7] (conflicts=0, R5).
// B: fragment-major global [kc][n(128)][8] — per-lane b128 loads straight to VGPRs
//    (L2-resident), register-double-buffered one iteration ahead.
// R10: EXACT R7 structure (158.5us best). R8 phase-split and R9 full-unroll both
//    failed to beat it — compiler already schedules this loop near-optimally.
// As points to 2*MT*64 u16 of LDS (two buffers).
template<int MT>   // 128 or 64
__device__ __forceinline__ void gemm_core(
    const u16* __restrict__ A, const u16* __restrict__ Btf,
    u16* As, f32x4 (&acc)[MT / 32][4]) {
  constexpr int MI = MT / 32;
  const int tid = threadIdx.x;
  const int wave = tid >> 6;
  const int lane = tid & 63;
  // lane l -> row +(l>>3), chunk col pc = l&7, logical col lc = pc ^ (l>>3)
  const size_t lnoff = (size_t)(lane >> 3) * Kk + (size_t)(((lane & 7) ^ (lane >> 3)) * 8);

  const int wm = (wave >> 1) * (MT / 2);  // wave 2x2 arrangement
  const int wn = (wave & 1) * 64;
  const int fr = lane & 15;            // A: m-in-16 / B: n-in-16
  const int q  = lane >> 4;            // k quad: holds k = kwin*32 + q*8 .. +7
  const int sw = fr & 7;               // row-swizzle for A frag reads

  // B frag pointer: elem offset kc*1024 + n*8, kc = kt/8 + ks*4 + q (q folded in)
  const u16* bptr = Btf + ((size_t)q * 128 + wn + fr) * 8;
  f16x8 bcur[8], bnxt[8];
  #pragma unroll
  for (int ks = 0; ks < 2; ks++)
    #pragma unroll
    for (int j = 0; j < 4; j++)
      bcur[ks * 4 + j] = *(const f16x8*)(bptr + (ks * 4) * 1024 + j * 128);

  #pragma unroll
  for (int i = 0; i < MI; i++)
    #pragma unroll
    for (int j = 0; j < 4; j++)
      #pragma unroll
      for (int r = 0; r < 4; r++) acc[i][j][r] = 0.0f;

  // prologue: stage window 0 into buf0 (latency exposed once)
  #pragma unroll
  for (int c = 0; c < MI; c++)
    gll16(A + lnoff + (size_t)((c * 4 + wave) * 8) * Kk, As + (c * 4 + wave) * 512);
  __syncthreads();

  for (int w = 0; w < Kk / 64; w++) {
    const int kt = w * 64;
    u16* cur = As + (w & 1) * (MT * 64);
    u16* nxt = As + ((w + 1) & 1) * (MT * 64);
    // stage next A window (overlaps with compute below; drained at loop-end barrier)
    if (w + 1 < Kk / 64) {
      #pragma unroll
      for (int c = 0; c < MI; c++)
        gll16(A + lnoff + (size_t)((c * 4 + wave) * 8) * Kk + kt + 64, nxt + (c * 4 + wave) * 512);
    }
    // prefetch next B window into regs (wrap on last iter; values unused)
    const int ktn = (kt + 64) & (Kk - 1);
    #pragma unroll
    for (int ks = 0; ks < 2; ks++)
      #pragma unroll
      for (int j = 0; j < 4; j++)
        bnxt[ks * 4 + j] = *(const f16x8*)(bptr + ((ktn >> 3) + ks * 4) * 1024 + j * 128);
    // compute current window
    #pragma unroll
    for (int ks = 0; ks < 2; ks++) {
      const int col = ((ks << 2) | q) ^ sw;   // phys 16B-chunk column (A swizzle)
      f16x8 ah[MI];
      #pragma unroll
      for (int i = 0; i < MI; i++)
        ah[i] = *(const f16x8*)(cur + (wm + i * 16 + fr) * 64 + col * 8);
      #pragma unroll
      for (int i = 0; i < MI; i++)
        #pragma unroll
        for (int j = 0; j < 4; j++)
          acc[i][j] = __builtin_amdgcn_mfma_f32_16x16x32_f16(ah[i], bcur[ks * 4 + j], acc[i][j], 0, 0, 0);
    }
    __syncthreads();   // single barrier: my ds_reads of cur done; all waves' stage of nxt drained
    #pragma unroll
    for (int t = 0; t < 8; t++) bcur[t] = bnxt[t];
  }
}

// C/D layout (measured m89/m91): col = lane&15, row = (lane>>4)*4 + reg

__global__ __launch_bounds__(256) void gemm_qkv(
    const u16* __restrict__ xh, const u16* __restrict__ wT,
    const float* __restrict__ bq, const float* __restrict__ bk, const float* __restrict__ bv,
    u16* __restrict__ q, u16* __restrict__ k, u16* __restrict__ v) {
  __shared__ u16 As[128 * 64 * 2];
  const int m0 = blockIdx.x * 128;
  const int z = blockIdx.z;            // proj*8 + h
  const int proj = z >> 3, h = z & 7;
  f32x4 acc[4][4];
  gemm_core<128>(xh + (size_t)m0 * Kk, wT + (size_t)z * (Ee * Kk), As, acc);

  u16* dst = proj == 0 ? q : (proj == 1 ? k : v);
  const float* bias = proj == 0 ? bq : (proj == 1 ? bk : bv);
  const int wave = threadIdx.x >> 6, lane = threadIdx.x & 63;
  const int wm = (wave >> 1) * 64, wn = (wave & 1) * 64;
  const int cn = lane & 15, rq4 = (lane >> 4) * 4;
  #pragma unroll
  for (int j = 0; j < 4; j++) {
    const int e = wn + j * 16 + cn;
    const float bb = bias[h * Ee + e];
    #pragma unroll
    for (int i = 0; i < 4; i++) {
      #pragma unroll
      for (int r = 0; r < 4; r++) {
        const int m = m0 + wm + i * 16 + rq4 + r;     // m = b*S + s
        const int b = m >> 11, s = m & (Ss - 1);
        dst[(((size_t)(b * Hh + h)) * Ss + s) * Ee + e] = f2h(acc[i][j][r] + bb);
      }
    }
  }
}

__global__ __launch_bounds__(256) void gemm_out(
    const u16* __restrict__ attn, const u16* __restrict__ woT,
    const float* __restrict__ bo, float* __restrict__ out) {
  __shared__ u16 As[64 * 64 * 2];
  const int m0 = blockIdx.x * 64;
  const int n0 = blockIdx.y * 128;
  f32x4 acc[2][4];
  gemm_core<64>(attn + (size_t)m0 * Kk, woT + (size_t)blockIdx.y * 131072, As, acc);
  const int wave = threadIdx.x >> 6, lane = threadIdx.x & 63;
  const int wm = (wave >> 1) * 32, wn = (wave & 1) * 64;
  const int cn = lane & 15, rq4 = (lane >> 4) * 4;
  #pragma unroll
  for (int j = 0; j < 4; j++) {
    const int n = n0 + wn + j * 16 + cn;
    const float bb = bo[n];
    #pragma unroll
    for (int i = 0; i < 2; i++) {
      #pragma unroll
      for (int r = 0; r < 4; r++) {
        const int m = m0 + wm + i * 16 + rq4 + r;
        out[(size_t)m * Dd + n] = acc[i][j][r] + bb;
      }
    }
  }
}

// ---------------- attention: 4 s per wave (16-lane groups), dwordx4 loads ----------------
// Each wave = four 16-lane groups, one (b,h,s) each; lane lx owns elements
// e0 = lx*8 .. +7 (16B dwordx4 per row).
// R10: V rows loaded in j-order — pos is GROUP-UNIFORM, so all 16 lanes read the
// same 256B row segment (coalesced, 4 lines/group) instead of the previous
// lx^t-order gather (16 scattered lines per instruction, 4x request count,
// 75% wasted line bandwidth). Weight distribution moves to the shuffle side:
// gj[j] = __shfl(w, gbase|j) (ds_bpermute, uniform index) replaces the XOR
// allgather — shuffle count unchanged (16 vs 15).
__global__ __launch_bounds__(256) void attn_kernel(
    const u16* __restrict__ q, const u16* __restrict__ k, const u16* __restrict__ v,
    const float* __restrict__ bk, const float* __restrict__ bv,
    const int* __restrict__ dil, u16* __restrict__ attn) {
  // XCD-contiguous swizzle: XCD i (= blockIdx%8 round-robin) gets a contiguous
  // blk range = 2 whole (b,h) panels -> disjoint ~3MB L2 working set per XCD.
  const int nblk = (Bb * Hh * Ss) / 16;           // 2048 blocks, 4 waves x 4 s
  const int blk = (blockIdx.x & 7) * (nblk / 8) + (blockIdx.x >> 3);
  const int wid = blk * 4 + (threadIdx.x >> 6);   // [0, 8192)
  const int lane = threadIdx.x & 63;
  const int grp = lane >> 4;                       // which s of this wave's 4
  const int lx = lane & 15;                        // lane within 16-group
  const int idx = wid * 4 + grp;                   // global (b,h,s) task
  const int s = idx & (Ss - 1);
  const int bh = idx >> 11;                        // b*H + h
  const int h = bh & 7, b = bh >> 3;
  const int d = dil[h];
  const size_t base = (size_t)bh * Ss * Ee;        // u16 elements
  const u16* kp = k + base;
  const u16* vp = v + base;
  const int e0 = lx * 8;
  const int off = (d * (KWW - 1)) >> 1;

  // q slice -> f32
  float qf[8];
  {
    uint4 qw = *(const uint4*)(q + base + (size_t)s * Ee + e0);
    qf[0] = h2f_lo(qw.x); qf[1] = h2f_hi(qw.x);
    qf[2] = h2f_lo(qw.y); qf[3] = h2f_hi(qw.y);
    qf[4] = h2f_lo(qw.z); qf[5] = h2f_hi(qw.z);
    qf[6] = h2f_lo(qw.w); qf[7] = h2f_hi(qw.w);
  }
  // bias slices (padded key/value = bias projection of zero-embedding)
  float bkf[8], bvf[8];
  {
    const float4 a0 = ((const float4*)(bk + h * Ee + e0))[0];
    const float4 a1 = ((const float4*)(bk + h * Ee + e0))[1];
    bkf[0]=a0.x; bkf[1]=a0.y; bkf[2]=a0.z; bkf[3]=a0.w;
    bkf[4]=a1.x; bkf[5]=a1.y; bkf[6]=a1.z; bkf[7]=a1.w;
    const float4 c0 = ((const float4*)(bv + h * Ee + e0))[0];
    const float4 c1 = ((const float4*)(bv + h * Ee + e0))[1];
    bvf[0]=c0.x; bvf[1]=c0.y; bvf[2]=c0.z; bvf[3]=c0.w;
    bvf[4]=c1.x; bvf[5]=c1.y; bvf[6]=c1.z; bvf[7]=c1.w;
  }
  float blog = 0.f;
  #pragma unroll
  for (int i = 0; i < 8; i++) blog += qf[i] * bkf[i];
  // packed f16 v-bias for OOB substitution at load time
  uint4 bvh;
  bvh.x = (uint32_t)f2h(bvf[0]) | ((uint32_t)f2h(bvf[1]) << 16);
  bvh.y = (uint32_t)f2h(bvf[2]) | ((uint32_t)f2h(bvf[3]) << 16);
  bvh.z = (uint32_t)f2h(bvf[4]) | ((uint32_t)f2h(bvf[5]) << 16);
  bvh.w = (uint32_t)f2h(bvf[6]) | ((uint32_t)f2h(bvf[7]) << 16);

  // ---- logit partials: lane lx holds partial (over its 8 elems) for ALL 16 j ----
  float logit[KWW];
  #pragma unroll
  for (int j = 0; j < KWW; j++) {
    const int pos = s + d * j - off;
    const int posc = min(max(pos, 0), Ss - 1);
    uint4 kw = *(const uint4*)(kp + (size_t)posc * Ee + e0);
    float t = qf[0] * h2f_lo(kw.x) + qf[1] * h2f_hi(kw.x)
            + qf[2] * h2f_lo(kw.y) + qf[3] * h2f_hi(kw.y)
            + qf[4] * h2f_lo(kw.z) + qf[5] * h2f_hi(kw.z)
            + qf[6] * h2f_lo(kw.w) + qf[7] * h2f_hi(kw.w);
    logit[j] = (pos >= 0 && pos < Ss) ? t : blog;
  }

  // ---- preload v rows in j order (pos group-uniform -> coalesced 256B/group) ----
  uint4 vrow[KWW];
  #pragma unroll
  for (int j = 0; j < KWW; j++) {
    const int pos = s + d * j - off;
    const int posc = min(max(pos, 0), Ss - 1);
    uint4 vw = *(const uint4*)(vp + (size_t)posc * Ee + e0);
    const bool ok = (pos >= 0) && (pos < Ss);
    vrow[j].x = ok ? vw.x : bvh.x;
    vrow[j].y = ok ? vw.y : bvh.y;
    vrow[j].z = ok ? vw.z : bvh.z;
    vrow[j].w = ok ? vw.w : bvh.w;
  }

  // ---- reduce-scatter within 16-lane groups: lane lx ends owning logit j = lx ----
  {
    const bool hi = (lx & 8) != 0;
    #pragma unroll
    for (int jj = 0; jj < 8; jj++) {
      float send = hi ? logit[jj] : logit[jj + 8];
      float recv = __shfl_xor(send, 8, 64);
      logit[jj] = (hi ? logit[jj + 8] : logit[jj]) + recv;
    }
  }
  {
    const bool hi = (lx & 4) != 0;
    #pragma unroll
    for (int jj = 0; jj < 4; jj++) {
      float send = hi ? logit[jj] : logit[jj + 4];
      float recv = __shfl_xor(send, 4, 64);
      logit[jj] = (hi ? logit[jj + 4] : logit[jj]) + recv;
    }
  }
  {
    const bool hi = (lx & 2) != 0;
    #pragma unroll
    for (int jj = 0; jj < 2; jj++) {
      float send = hi ? logit[jj] : logit[jj + 2];
      float recv = __shfl_xor(send, 2, 64);
      logit[jj] = (hi ? logit[jj + 2] : logit[jj]) + recv;
    }
  }
  float own;
  {
    const bool hi = (lx & 1) != 0;
    float send = hi ? logit[0] : logit[1];
    float recv = __shfl_xor(send, 1, 64);
    own = (hi ? logit[1] : logit[0]) + recv;   // own = full logit for j = lx
  }

  // ---- softmax over the 16 j's (one per lane in the group) ----
  float mx = own;
  mx = fmaxf(mx, __shfl_xor(mx, 1, 64));
  mx = fmaxf(mx, __shfl_xor(mx, 2, 64));
  mx = fmaxf(mx, __shfl_xor(mx, 4, 64));
  mx = fmaxf(mx, __shfl_xor(mx, 8, 64));
  float w = __expf(own - mx);
  float sum = w;
  sum += __shfl_xor(sum, 1, 64);
  sum += __shfl_xor(sum, 2, 64);
  sum += __shfl_xor(sum, 4, 64);
  sum += __shfl_xor(sum, 8, 64);
  w *= 1.0f / (sum * 11.313708498984760f);  // /Z /sqrt(E), post-softmax quirk

  // ---- gather per-j weights: gj[j] = w of lane (gbase+j); uniform-index bpermute ----
  const int gbase = lane & 48;
  float gj[KWW];
  #pragma unroll
  for (int j = 0; j < KWW; j++)
    gj[j] = __shfl(w, gbase | j, 64);

  // ---- PV: acc_e = sum_j gj[j] * v[j][e] ----
  float acc[8];
  #pragma unroll
  for (int i = 0; i < 8; i++) acc[i] = 0.f;
  #pragma unroll
  for (int j = 0; j < KWW; j++) {
    const float wt = gj[j];
    acc[0] += wt * h2f_lo(vrow[j].x);
    acc[1] += wt * h2f_hi(vrow[j].x);
    acc[2] += wt * h2f_lo(vrow[j].y);
    acc[3] += wt * h2f_hi(vrow[j].y);
    acc[4] += wt * h2f_lo(vrow[j].z);
    acc[5] += wt * h2f_hi(vrow[j].z);
    acc[6] += wt * h2f_lo(vrow[j].w);
    acc[7] += wt * h2f_hi(vrow[j].w);
  }

  // write fp16 attn as A-matrix [b*S+s][h*E+e], 16B per lane (coalesced per group)
  uint4 o;
  o.x = (uint32_t)f2h(acc[0]) | ((uint32_t)f2h(acc[1]) << 16);
  o.y = (uint32_t)f2h(acc[2]) | ((uint32_t)f2h(acc[3]) << 16);
  o.z = (uint32_t)f2h(acc[4]) | ((uint32_t)f2h(acc[5]) << 16);
  o.w = (uint32_t)f2h(acc[6]) | ((uint32_t)f2h(acc[7]) << 16);
  *(uint4*)(attn + (size_t)(b * Ss + s) * (Hh * Ee) + h * Ee + e0) = o;
}

// ---------------- launcher ----------------
extern "C" void kernel_launch(void* const* d_in, const int* in_sizes, int n_in,
                              void* d_out, int out_size, void* d_ws, size_t ws_size,
                              hipStream_t stream) {
  (void)in_sizes; (void)n_in; (void)out_size; (void)ws_size;
  const float* x  = (const float*)d_in[0];
  const float* Wq = (const float*)d_in[1];
  const float* bq = (const float*)d_in[2];
  const float* Wk = (const float*)d_in[3];
  const float* bk = (const float*)d_in[4];
  const float* Wv = (const float*)d_in[5];
  const float* bv = (const float*)d_in[6];
  const float* Wo = (const float*)d_in[7];
  const float* bo = (const float*)d_in[8];
  const int* dil  = (const int*)d_in[9];
  float* out = (float*)d_out;

  char* ws = (char*)d_ws;
  u16* xh  = (u16*)ws;  ws += (size_t)Mm * Kk * 2;             // 8 MB  [m][d] f16
  u16* wT  = (u16*)ws;  ws += (size_t)24 * Ee * Kk * 2;        // 6 MB  frag-major [z][kc][n][8]
  u16* woT = (u16*)ws;  ws += (size_t)Kk * Dd * 2;             // 2 MB  frag-major [nb][kc][nn][8]
  u16* q = (u16*)ws; ws += (size_t)Bb * Hh * Ss * Ee * 2;      // 8 MB each, f16 [bh][s][e]
  u16* k = (u16*)ws; ws += (size_t)Bb * Hh * Ss * Ee * 2;
  u16* v = (u16*)ws; ws += (size_t)Bb * Hh * Ss * Ee * 2;
  // attn (8 MB f16) aliases xh — dead after gemm_qkv (stream-ordered)
  u16* attn = xh;

  prep<<<8192, 256, 0, stream>>>(x, Wq, Wk, Wv, Wo, xh, wT, woT);
  gemm_qkv<<<dim3(Mm / 128, 1, 24), 256, 0, stream>>>(xh, wT, bq, bk, bv, q, k, v);
  attn_kernel<<<(Bb * Hh * Ss) / 16, 256, 0, stream>>>(q, k, v, bk, bv, dil, attn);
  gemm_out<<<dim3(Mm / 64, Dd / 128), 256, 0, stream>>>(attn, woT, bo, out);
}